// Round 17
// baseline (144.997 us; speedup 1.0000x reference)
//
#include <hip/hip_runtime.h>

#define WL 512   // window_len (t and o dims)
#define NV 64    // n_var
#define LR 16    // low rank
#define NB 512   // batch

__device__ __forceinline__ float tanh_fast(float x) {
    // tanh(x) = 1 - 2/(exp(2x)+1); exact at +-inf saturation, ~1e-7 abs err
    float e = __expf(2.0f * x);
    return 1.0f - 2.0f / (e + 1.0f);
}

// K1: tmp[b,k,v] = sum_t tanh(g[v]*x[b,t,v]) * A[t,k]
// grid = 512 (one block per b), block = 1024 threads (16 waves).
// (byte-identical to R7's verified version)
__global__ __launch_bounds__(1024, 8) void k_tmp(
    const float* __restrict__ x, const float* __restrict__ gating,
    const float* __restrict__ A, float* __restrict__ tmp)
{
    __shared__ float red[16 * LR * NV];  // 64 KiB (16 partials x 1024 (k,v))
    const int tid = threadIdx.x;
    const int b = blockIdx.x;

    const int v = tid & 63;
    const int tg = __builtin_amdgcn_readfirstlane(tid >> 6);
    const float g = gating[v];

    float acc[LR];
#pragma unroll
    for (int k = 0; k < LR; ++k) acc[k] = 0.f;

    const float* xb = x + (size_t)b * (WL * NV) + (size_t)tg * 32 * NV + v;
    const float* Abase = A + (size_t)tg * 32 * LR;

#pragma unroll 4
    for (int i = 0; i < 32; ++i) {
        const float x1 = tanh_fast(g * xb[i * NV]);      // 256B/wave, coalesced
        const float* Ar = Abase + i * LR;                // wave-uniform -> s_load
#pragma unroll
        for (int k = 0; k < LR; ++k) acc[k] = fmaf(x1, Ar[k], acc[k]);
    }

#pragma unroll
    for (int k = 0; k < LR; ++k) red[(tg * LR + k) * NV + v] = acc[k];
    __syncthreads();

    {
        const int p = tid;
        float s = 0.f;
#pragma unroll
        for (int t = 0; t < 16; ++t) s += red[t * (LR * NV) + p];
        tmp[(size_t)b * (LR * NV) + p] = s;
    }
}

// K2: out[b,o,v] = x[b,o,v] + bias[o,v] + sum_k tmp[b,k,v]*B[k,o,v]
// grid = (64 b-chunks of 8) x (32 o-tiles of 16), block = 256 (4 waves)
//   == R2's proven 31.3us structure, ONE change: FLOAT4 STREAMS ==
//
// Evidence: harness fill = 6.9 TB/s with 16B/lane f4 stores; our dword
// (4B/lane) streams measured 3.4-4.8 TB/s across every variant. R2's K2
// issues 88 wave-VMEM per wave-batch, all 256B-granule. Lane remap
// lane = oL*16+vq (oL=lane>>4: o-row; vq=lane&15: v-quad): the wave's 4
// ADJACENT o-rows x 64 v = one fully contiguous 1KB per x-load and per
// store instruction; tmp/B/bias also f4. 34 wave-VMEM per wave-batch.
// Everything else untouched: B+tmp refetched per batch (L1-hot; R15
// proved L1 bytes don't bind; keeps VGPR demand ~60 under the measured
// 64 half-grant — no allocator fight), launch_bounds(256,4) (R6: 37%
// occ), FMA order bias -> k-ascending -> x (absmax identical).
__global__ __launch_bounds__(256, 4) void k_out(
    const float* __restrict__ x, const float* __restrict__ bias,
    const float* __restrict__ Bm, const float* __restrict__ tmp,
    float* __restrict__ out)
{
    const int tid = threadIdx.x;
    const int lane = tid & 63;
    const int w = tid >> 6;                 // wave 0..3
    const int oL = lane >> 4;               // 0..3: which o-row in the wave's quad
    const int vq = lane & 15;               // v-quad index: v = vq*4..vq*4+3
    const int o = blockIdx.y * 16 + w * 4 + oL;
    const int b0 = blockIdx.x * 8;

    const float4 bias4 = *(const float4*)(bias + (size_t)o * NV + vq * 4);

#pragma unroll 1
    for (int bi = 0; bi < 8; ++bi) {
        const int b = b0 + bi;
        const float* tb = tmp + (size_t)b * (LR * NV) + vq * 4;
        const float* Bb = Bm + (size_t)o * NV + vq * 4;

        // x: one f4 per lane; wave = 4 adjacent o-rows = contiguous 1KB
        const float4 x4 = *(const float4*)(x + ((size_t)b * WL + o) * NV + vq * 4);

        float4 acc = bias4;
#pragma unroll
        for (int k = 0; k < LR; ++k) {
            const float4 t4 = *(const float4*)(tb + k * NV);          // 256B unique, L1-hot
            const float4 B4 = *(const float4*)(Bb + (size_t)k * (WL * NV)); // 1KB, L1-hot
            acc.x = fmaf(t4.x, B4.x, acc.x);
            acc.y = fmaf(t4.y, B4.y, acc.y);
            acc.z = fmaf(t4.z, B4.z, acc.z);
            acc.w = fmaf(t4.w, B4.w, acc.w);
        }
        acc.x += x4.x; acc.y += x4.y; acc.z += x4.z; acc.w += x4.w;

        // store: contiguous 1KB per wave instruction
        *(float4*)(out + ((size_t)b * WL + o) * NV + vq * 4) = acc;
    }
}

extern "C" void kernel_launch(void* const* d_in, const int* in_sizes, int n_in,
                              void* d_out, int out_size, void* d_ws, size_t ws_size,
                              hipStream_t stream) {
    const float* x      = (const float*)d_in[0];  // [512,512,64,1]
    const float* gating = (const float*)d_in[1];  // [64]
    const float* bias   = (const float*)d_in[2];  // [512,64]
    const float* A      = (const float*)d_in[3];  // [512,16]
    const float* Bm     = (const float*)d_in[4];  // [16,512,64]
    float* out = (float*)d_out;
    float* tmp = (float*)d_ws;                    // 2 MiB scratch ([b,k,v])

    k_tmp<<<NB, 1024, 0, stream>>>(x, gating, A, tmp);
    k_out<<<dim3(64, 32), 256, 0, stream>>>(x, bias, Bm, tmp, out);
}

// Round 18
// 57.904 us; speedup vs baseline: 2.5041x; 2.5041x over previous
//
#include <hip/hip_runtime.h>

#define WL 512   // window_len (t and o dims)
#define NV 64    // n_var
#define LR 16    // low rank
#define NB 512   // batch
#define BB 16    // batches per k_out block
#define OO 16    // o-rows per k_out block
#define BPAD 4   // pad floats per o-row in B_lds (banks staggered across oL groups)
#define BSTRIDE (LR * NV + BPAD)   // 1028 floats per o-row

__device__ __forceinline__ float tanh_fast(float x) {
    // tanh(x) = 1 - 2/(exp(2x)+1); exact at +-inf saturation, ~1e-7 abs err
    float e = __expf(2.0f * x);
    return 1.0f - 2.0f / (e + 1.0f);
}

// K1: tmp[b,k,v] = sum_t tanh(g[v]*x[b,t,v]) * A[t,k]
// grid = 512 (one block per b), block = 1024 threads (16 waves).
// (byte-identical to R7's verified version; ~16us standalone)
__global__ __launch_bounds__(1024, 8) void k_tmp(
    const float* __restrict__ x, const float* __restrict__ gating,
    const float* __restrict__ A, float* __restrict__ tmp)
{
    __shared__ float red[16 * LR * NV];  // 64 KiB (16 partials x 1024 (k,v))
    const int tid = threadIdx.x;
    const int b = blockIdx.x;

    const int v = tid & 63;
    const int tg = __builtin_amdgcn_readfirstlane(tid >> 6);
    const float g = gating[v];

    float acc[LR];
#pragma unroll
    for (int k = 0; k < LR; ++k) acc[k] = 0.f;

    const float* xb = x + (size_t)b * (WL * NV) + (size_t)tg * 32 * NV + v;
    const float* Abase = A + (size_t)tg * 32 * LR;

#pragma unroll 4
    for (int i = 0; i < 32; ++i) {
        const float x1 = tanh_fast(g * xb[i * NV]);      // 256B/wave, coalesced
        const float* Ar = Abase + i * LR;                // wave-uniform -> s_load
#pragma unroll
        for (int k = 0; k < LR; ++k) acc[k] = fmaf(x1, Ar[k], acc[k]);
    }

#pragma unroll
    for (int k = 0; k < LR; ++k) red[(tg * LR + k) * NV + v] = acc[k];
    __syncthreads();

    {
        const int p = tid;
        float s = 0.f;
#pragma unroll
        for (int t = 0; t < 16; ++t) s += red[t * (LR * NV) + p];
        tmp[(size_t)b * (LR * NV) + p] = s;
    }
}

// K2: out[b,o,v] = x[b,o,v] + bias[o,v] + sum_k tmp[b,k,v]*B[k,o,v]
// grid = (32 b-chunks of 16) x (32 o-tiles of 16), block = 1024 (16 waves)
//
// DUAL-WALL FIX. K2 has TWO overlapped ~31us terms; every prior variant
// fixed one and kept (or worsened) the other:
//  (1) B-refetch: 1.07GB through L2 (R2) -> B_lds staged ONCE per block
//      (64MB total). tmp also staged (T_lds) so the R15/R16 tmp-duplication
//      (0.5GB) is gone too.
//  (2) dword x/out streams (~4.2TB/s measured ceiling) -> f4 lane remap
//      (lane = oL*16+vq): x-loads and out-stores are 1KB contiguous per
//      wave instruction (the 6.9TB/s fill's pattern).
// Prior failure modes engineered out: occupancy (1024-thr block, 128KB LDS
// -> 1 block/CU = 16 waves/CU, vs R11's 8); spill (k-loop unroll 2 -> ~45
// live VGPR vs R17's ~128 -> no scratch); B_lds o-rows padded +4 floats so
// the 4 oL-groups hit staggered banks (uniform ~2-way = free).
// wave w: o-quad = (w&3)*4 + oL, b-quad = (w>>2)*4 + bb(loop 0..3).
// FMA order bias -> k-ascending -> x identical to R2 -> absmax unchanged.
__global__ __launch_bounds__(1024, 1) void k_out(
    const float* __restrict__ x, const float* __restrict__ bias,
    const float* __restrict__ Bm, const float* __restrict__ tmp,
    float* __restrict__ out)
{
    __shared__ float B_lds[OO * BSTRIDE];   // [o][k][v] + pad = 65792 B
    __shared__ float T_lds[BB * LR * NV];   // [b][k][v] linear   = 65536 B
    const int tid = threadIdx.x;
    const int lane = tid & 63;
    const int w = tid >> 6;                 // wave 0..15
    const int oL = lane >> 4;               // 0..3
    const int vq = lane & 15;               // v = vq*4 .. vq*4+3
    const int o0 = blockIdx.y * OO;
    const int b0 = blockIdx.x * BB;

    // ---- stage B slice: 16o x 16k x 64v = 4096 float4, 4 per thread ----
#pragma unroll
    for (int it = 0; it < 4; ++it) {
        const int fidx = it * 1024 + tid;   // 0..4095
        const int v4 = fidx & 15;
        const int ko = fidx >> 4;           // 0..255
        const int k  = ko & 15;
        const int ol = ko >> 4;             // 0..15
        const float4 val = *(const float4*)(Bm + ((size_t)k * WL + (o0 + ol)) * NV + v4 * 4);
        *(float4*)(B_lds + ol * BSTRIDE + k * NV + v4 * 4) = val;
    }
    // ---- stage tmp slice: 16 batches x 1024 floats, fully linear ----
    {
        const float4* src = (const float4*)(tmp + (size_t)b0 * (LR * NV));
        float4* dst = (float4*)T_lds;
#pragma unroll
        for (int it = 0; it < 4; ++it) dst[it * 1024 + tid] = src[it * 1024 + tid];
    }
    __syncthreads();

    const int o_local = (w & 3) * 4 + oL;
    const int o = o0 + o_local;
    const int bq = (w >> 2) * 4;

    const float4 bias4 = *(const float4*)(bias + (size_t)o * NV + vq * 4);
    const float* Bb = B_lds + o_local * BSTRIDE + vq * 4;

#pragma unroll 1
    for (int bb = 0; bb < 4; ++bb) {
        const int b_local = bq + bb;
        const int b = b0 + b_local;
        const float* tb = T_lds + b_local * (LR * NV) + vq * 4;

        // f4 x load: wave's 4 adjacent o-rows x 64 v = 1KB contiguous
        const float4 x4 = *(const float4*)(x + ((size_t)b * WL + o) * NV + vq * 4);

        float4 acc = bias4;
#pragma unroll 2
        for (int k = 0; k < LR; ++k) {
            const float4 t4 = *(const float4*)(tb + k * NV);   // broadcast-ish, free
            const float4 B4 = *(const float4*)(Bb + k * NV);   // staggered banks
            acc.x = fmaf(t4.x, B4.x, acc.x);
            acc.y = fmaf(t4.y, B4.y, acc.y);
            acc.z = fmaf(t4.z, B4.z, acc.z);
            acc.w = fmaf(t4.w, B4.w, acc.w);
        }
        acc.x += x4.x; acc.y += x4.y; acc.z += x4.z; acc.w += x4.w;

        // f4 store: 1KB contiguous per wave instruction
        *(float4*)(out + ((size_t)b * WL + o) * NV + vq * 4) = acc;
    }
}

extern "C" void kernel_launch(void* const* d_in, const int* in_sizes, int n_in,
                              void* d_out, int out_size, void* d_ws, size_t ws_size,
                              hipStream_t stream) {
    const float* x      = (const float*)d_in[0];  // [512,512,64,1]
    const float* gating = (const float*)d_in[1];  // [64]
    const float* bias   = (const float*)d_in[2];  // [512,64]
    const float* A      = (const float*)d_in[3];  // [512,16]
    const float* Bm     = (const float*)d_in[4];  // [16,512,64]
    float* out = (float*)d_out;
    float* tmp = (float*)d_ws;                    // 2 MiB scratch ([b,k,v])

    k_tmp<<<NB, 1024, 0, stream>>>(x, gating, A, tmp);
    k_out<<<dim3(32, 32), 1024, 0, stream>>>(x, bias, Bm, tmp, out);
}